// Round 5
// baseline (98.812 us; speedup 1.0000x reference)
//
#include <hip/hip_runtime.h>
#include <stdint.h>

#define NQ 10
#define NL 4

typedef unsigned int u32;
typedef _Float16 f16x8 __attribute__((ext_vector_type(8)));
typedef float f32x16 __attribute__((ext_vector_type(16)));
typedef u32 u32x4 __attribute__((ext_vector_type(4)));

// CNOT-ring permutation F = X ∘ (Gray⊗Gray), gather convention (R10/R11-validated):
// Gray folded into prep; runtime X: row ^= C0*16, col ^= R0*31, in registers.
//
// sigma slot-order (R12): every MFMA operand fragment uses slot->k map
// sigma(s): k = kh*16 + j2*8 + hf*4 + j1j0. A C-layout output value gi lands at
// A-frag slot (kh=gi>>3, j=gi&7) in the SAME lane -> layout conversion = pk2 only.
//
// X-step under sigma (R12-validated exact form): dest slot j even (R0=0):
// in-lane, word select by own c0. Dest slot j odd (R0=1): via lane C^31
// (ds_swizzle); the word a lane SENDS for kh0-odd slots is xe1, for kh1-odd
// slots is xe0.
//
// Epilogue (R1-validated): E = mfma(P as A, Srow as B) -> E[c][q], q = lane.
// Column signs via parity words SM(Mcol_q); one shfl(^32); lanes 0..9 store.
//
// R4 post-mortem: failures correlate with __launch_bounds__(256,4) (forced
// 128-reg cap on a kernel whose live accumulator state exceeds it), NOT with
// the nVi algebra (bit-exact) or X-step rewrite (word-verified). R5 bisects:
// base = R2 (passing) + ONLY the nVi static frags; plain __launch_bounds__(256).
// HARD CONSTRAINTS: frag table <= 46 frags (ws >= 47104 B proven by R1);
// never force waves-per-EU via launch_bounds on this kernel.
// frag table (42): f = l*8 + mat*4 + part*2 + kh (0..31); 32,33 = Srow;
//                  34 + l*2 + kh = nVi (exact -Vi).
//
// F^-1 row sign masks (Srow frags): Mrow: q0=0x0F q1=0x18 q2=0x1C q3=0x1E q>=4=0x1F

// ---------- helpers ----------
__device__ __forceinline__ f32x16 mfma16(f16x8 a, f16x8 b, f32x16 c) {
    return __builtin_amdgcn_mfma_f32_32x32x16_f16(a, b, c, 0, 0, 0);
}
__device__ __forceinline__ f32x16 zero16() {
    f32x16 z;
#pragma unroll
    for (int i = 0; i < 16; i++) z[i] = 0.f;
    return z;
}
__device__ __forceinline__ f16x8 negf(f16x8 v) {
    u32x4 u = __builtin_bit_cast(u32x4, v);
#pragma unroll
    for (int i = 0; i < 4; i++) u[i] ^= 0x80008000u;
    return __builtin_bit_cast(f16x8, u);
}
__device__ __forceinline__ u32 pk2(float a, float b) {
    auto h = __builtin_amdgcn_cvt_pkrtz(a, b);
    return __builtin_bit_cast(u32, h);
}
// result = lo16(x) | hi16(s)<<16
__device__ __forceinline__ u32 mixhl(u32 s, u32 x) {
    return __builtin_amdgcn_perm(s, x, 0x07060100u);
}
__device__ __forceinline__ f16x8 mk8(u32 a, u32 b, u32 c, u32 d) {
    u32x4 v; v[0] = a; v[1] = b; v[2] = c; v[3] = d;
    return __builtin_bit_cast(f16x8, v);
}
template <int MASK>
__device__ __forceinline__ u32 swzu(u32 v) {
    return (u32)__builtin_amdgcn_ds_swizzle((int)v, (MASK << 10) | 0x1F);
}
__device__ __forceinline__ void cmulh(float ar, float ai, float br, float bi, float& cr, float& ci) {
    cr = ar * br - ai * bi;
    ci = ar * bi + ai * br;
}

// ---------- prep: fused gates -> W,V frags (+ nVi copies, Srow) in d_ws ----------
// Launch <<<8,256>>> (2048-thread index space). Every block computes its own g[].
__global__ void tq_prep(const float* __restrict__ theta, uint16_t* __restrict__ frag) {
    __shared__ float g[NL * NQ][8];
    int tt = threadIdx.x;
    if (tt < NL * NQ) {
        float hx = 0.5f * theta[tt * 3 + 0];
        float hy = 0.5f * theta[tt * 3 + 1];
        float hz = 0.5f * theta[tt * 3 + 2];
        float cx = cosf(hx), sx = sinf(hx);
        float cy = cosf(hy), sy = sinf(hy);
        float cz = cosf(hz), sz = sinf(hz);
        float m00r = cx * cy, m00i = -sx * sy;
        float m01r = -cx * sy, m01i = -sx * cy;
        float m10r = cx * sy, m10i = -sx * cy;
        float m11r = cx * cy, m11i = sx * sy;
        float g00r, g00i, g01r, g01i, g10r, g10i, g11r, g11i;
        cmulh(m00r, m00i, cz, -sz, g00r, g00i);
        cmulh(m10r, m10i, cz, -sz, g10r, g10i);
        cmulh(m01r, m01i, cz, sz, g01r, g01i);
        cmulh(m11r, m11i, cz, sz, g11r, g11i);
        g[tt][0] = g00r; g[tt][1] = g00i; g[tt][2] = g01r; g[tt][3] = g01i;
        g[tt][4] = g10r; g[tt][5] = g10i; g[tt][6] = g11r; g[tt][7] = g11i;
    }
    __syncthreads();
    int t = blockIdx.x * blockDim.x + tt;  // 0..2047
    int lane = t & 63, kh = (t >> 6) & 1, part = (t >> 7) & 1, mat = (t >> 8) & 1, l = t >> 9;
    int mn = lane & 31, hf = (lane >> 5) & 1;
    int mne = (l < NL - 1) ? ((mn ^ (mn >> 1)) & 31) : mn;  // Gray fold for layers 0..2
    // negated copy only for Vi (mat=1, part=1): f = 34 + l*2 + kh  (42 frags total)
    uint16_t* nout = (part == 1 && mat == 1)
                         ? (frag + (((34 + l * 2 + kh) * 64) + lane) * 8)
                         : (uint16_t*)0;
#pragma unroll
    for (int j = 0; j < 8; j++) {
        int k = kh * 16 + ((j >> 2)) * 8 + hf * 4 + (j & 3);  // sigma(slot)
        float pr = 1.f, pi = 0.f;
#pragma unroll
        for (int u = 0; u < 5; u++) {
            int q = mat ? (5 + u) : u;
            int bi_ = (k >> (4 - u)) & 1;
            int bo_ = (mne >> (4 - u)) & 1;
            const float* gg = g[l * NQ + q];
            float er = gg[(bi_ * 2 + bo_) * 2 + 0];
            float ei = gg[(bi_ * 2 + bo_) * 2 + 1];
            float nr, ni;
            cmulh(pr, pi, er, ei, nr, ni);
            pr = nr;
            pi = ni;
        }
        float v = part ? pi : pr;
        _Float16 h = (_Float16)v;
        unsigned short hb = __builtin_bit_cast(unsigned short, h);
        frag[t * 8 + j] = hb;
        if (nout) nout[j] = hb ^ 0x8000u;  // exact sign flip
    }
    // Srow sign frags (f=32,33): element(lane q, slot s) = (-1)^par(sigma(s) & Mrow(q))
    if (blockIdx.x == 0 && tt < 128) {
        int ln = tt & 63, kh2 = tt >> 6;
        int q = ln & 31, hf2 = (ln >> 5) & 1;
        u32 M = (q == 0) ? 0xFu : (q == 1) ? 0x18u : (q == 2) ? 0x1Cu : (q == 3) ? 0x1Eu : 0x1Fu;
        uint16_t* o = frag + ((32 + kh2) * 64 + ln) * 8;
#pragma unroll
        for (int j = 0; j < 8; j++) {
            int k = kh2 * 16 + ((j >> 2)) * 8 + hf2 * 4 + (j & 3);  // sigma(slot)
            float v = (__builtin_popcount((u32)k & M) & 1) ? -1.f : 1.f;
            _Float16 h = (_Float16)v;
            o[j] = __builtin_bit_cast(unsigned short, h);
        }
    }
}

// ---------- main: one wave per sample; zero LDS allocation ----------
__global__ __launch_bounds__(256) void tq_main(
    const float* __restrict__ x, const float* __restrict__ encW,
    const float* __restrict__ encb, const uint16_t* __restrict__ frag,
    float* __restrict__ out, int batch) {
    int tid = threadIdx.x;
    int wave = (blockIdx.x * blockDim.x + tid) >> 6;
    int lane = tid & 63;
    if (wave >= batch) return;
    const int col = lane & 31;
    const int half_ = lane >> 5;
    const bool c0 = (lane & 1) != 0;

    // ---- encoding: RY(enc) product state, built directly as sigma-slot A-frag ----
    float x0 = x[wave * 3 + 0], x1 = x[wave * 3 + 1], x2 = x[wave * 3 + 2];
    float hc = 1.f, hs = 0.f;
    if (lane < NQ) {
        float tta = 3.14159265358979323846f *
                    tanhf(x0 * encW[lane * 3 + 0] + x1 * encW[lane * 3 + 1] +
                          x2 * encW[lane * 3 + 2] + encb[lane]);
        float h = 0.5f * tta;
        hc = cosf(h);
        hs = sinf(h);
    }
    float fcv[NQ], fsv[NQ];
#pragma unroll
    for (int q = 0; q < NQ; q++) {
        fcv[q] = __shfl(hc, q, 64);
        fsv[q] = __shfl(hs, q, 64);
    }
    float colf = 1.f;
    colf *= ((col >> 4) & 1) ? -fsv[5] : fcv[5];
    colf *= ((col >> 3) & 1) ? -fsv[6] : fcv[6];
    colf *= ((col >> 2) & 1) ? -fsv[7] : fcv[7];
    colf *= ((col >> 1) & 1) ? -fsv[8] : fcv[8];
    colf *= (col & 1) ? -fsv[9] : fcv[9];
    // row r = sigma(slot): q0<-kh, q1<-j2, q2<-hf, q3<-j1, q4<-j0
    float f2h = half_ ? -fsv[2] : fcv[2];
    float gj[8];
#pragma unroll
    for (int j = 0; j < 8; j++) {
        gj[j] = ((j & 4) ? -fsv[1] : fcv[1]) * ((j & 2) ? -fsv[3] : fcv[3]) *
                ((j & 1) ? -fsv[4] : fcv[4]);
    }
    f16x8 Sr0, Sr1, Si0, Si1;
#pragma unroll
    for (int j = 0; j < 8; j++) {
        Sr0[j] = (_Float16)(fcv[0] * f2h * gj[j] * colf);
        Sr1[j] = (_Float16)(-fsv[0] * f2h * gj[j] * colf);
        Si0[j] = (_Float16)0.f;
        Si1[j] = (_Float16)0.f;
    }

    const f16x8* fr = (const f16x8*)frag;
#define FRAG(f) fr[((f)*64) + lane]

    f32x16 Ur, Ui;
#pragma unroll
    for (int l = 0; l < NL; l++) {
        f16x8 Wr0 = FRAG(8 * l + 0), Wr1 = FRAG(8 * l + 1);
        f16x8 Wi0 = FRAG(8 * l + 2), Wi1 = FRAG(8 * l + 3);
        f16x8 Vr0 = FRAG(8 * l + 4), Vr1 = FRAG(8 * l + 5);
        f16x8 Vi0 = FRAG(8 * l + 6), Vi1 = FRAG(8 * l + 7);
        f16x8 nVi0 = FRAG(34 + l * 2 + 0), nVi1 = FRAG(34 + l * 2 + 1);

        // GEMM1': T' = S^T * W^T = T^T (S-frag as A; W-frag as B; both sigma-ordered)
        f32x16 Tr = zero16(), Ti = zero16();
        Tr = mfma16(Sr0, Wr0, Tr);
        Tr = mfma16(Sr1, Wr1, Tr);
        Ti = mfma16(Sr0, Wi0, Ti);
        Ti = mfma16(Sr1, Wi1, Ti);
        if (l > 0) {
            f16x8 nSi0 = negf(Si0), nSi1 = negf(Si1);  // off critical path
            Tr = mfma16(nSi0, Wi0, Tr);
            Tr = mfma16(nSi1, Wi1, Tr);
            Ti = mfma16(Si0, Wr0, Ti);
            Ti = mfma16(Si1, Wr1, Ti);
        }

        // C(T') -> sigma-slot A-frag(T): pure pack, same lane (no DS, no selects)
        f16x8 TAr0, TAr1, TAi0, TAi1;
        {
            u32 a0[4], a1[4], b0[4], b1[4];
#pragma unroll
            for (int p = 0; p < 4; p++) {
                a0[p] = pk2(Tr[2 * p], Tr[2 * p + 1]);
                a1[p] = pk2(Tr[8 + 2 * p], Tr[8 + 2 * p + 1]);
                b0[p] = pk2(Ti[2 * p], Ti[2 * p + 1]);
                b1[p] = pk2(Ti[8 + 2 * p], Ti[8 + 2 * p + 1]);
            }
            TAr0 = mk8(a0[0], a0[1], a0[2], a0[3]);
            TAr1 = mk8(a1[0], a1[1], a1[2], a1[3]);
            TAi0 = mk8(b0[0], b0[1], b0[2], b0[3]);
            TAi1 = mk8(b1[0], b1[1], b1[2], b1[3]);
        }

        // GEMM2: U = T * V (imag negation via static nVi frags, exact:
        // TAi*(-Vi) == (-TAi)*Vi; removes 8 xors from the pack->GEMM2 path)
        Ur = zero16();
        Ui = zero16();
        Ur = mfma16(TAr0, Vr0, Ur);
        Ur = mfma16(TAr1, Vr1, Ur);
        Ur = mfma16(TAi0, nVi0, Ur);
        Ur = mfma16(TAi1, nVi1, Ur);
        Ui = mfma16(TAr0, Vi0, Ui);
        Ui = mfma16(TAr1, Vi1, Ui);
        Ui = mfma16(TAi0, Vr0, Ui);
        Ui = mfma16(TAi1, Vr1, Ui);

        if (l < NL - 1) {
            // X-step + sigma A-frag assembly (R2-exact validated form):
            // word wr0[p]/wr1[p] = rows gi=(2p,2p+1) of kh-group 0/1.
            // even slots (R0=0, in-lane):  kh0 <- xe0 = c0?wr1:wr0, kh1 <- xe1
            // odd  slots (R0=1, via ^31): kh0 hi16 <- swz(xe1), kh1 hi16 <- swz(xe0)
            u32 wr0[4], wr1[4], wi0[4], wi1[4];
#pragma unroll
            for (int p = 0; p < 4; p++) {
                wr0[p] = pk2(Ur[2 * p], Ur[2 * p + 1]);
                wr1[p] = pk2(Ur[8 + 2 * p], Ur[8 + 2 * p + 1]);
                wi0[p] = pk2(Ui[2 * p], Ui[2 * p + 1]);
                wi1[p] = pk2(Ui[8 + 2 * p], Ui[8 + 2 * p + 1]);
            }
            u32 s0[4], s1[4], t0[4], t1[4];
#pragma unroll
            for (int p = 0; p < 4; p++) {
                u32 xe0r = c0 ? wr1[p] : wr0[p];
                u32 xe1r = c0 ? wr0[p] : wr1[p];
                u32 xe0i = c0 ? wi1[p] : wi0[p];
                u32 xe1i = c0 ? wi0[p] : wi1[p];
                s0[p] = mixhl(swzu<0x1F>(xe1r), xe0r);
                s1[p] = mixhl(swzu<0x1F>(xe0r), xe1r);
                t0[p] = mixhl(swzu<0x1F>(xe1i), xe0i);
                t1[p] = mixhl(swzu<0x1F>(xe0i), xe1i);
            }
            Sr0 = mk8(s0[0], s0[1], s0[2], s0[3]);
            Sr1 = mk8(s1[0], s1[1], s1[2], s1[3]);
            Si0 = mk8(t0[0], t0[1], t0[2], t0[3]);
            Si1 = mk8(t1[0], t1[1], t1[2], t1[3]);
        }
    }

    // ---- epilogue: E = P^T * Srow^T via MFMA(P as A, Srow as B) -> q = lane ----
    f32x16 P;
#pragma unroll
    for (int gi = 0; gi < 16; gi++) P[gi] = Ur[gi] * Ur[gi] + Ui[gi] * Ui[gi];
    f16x8 PB0, PB1;
    {
        u32 p0[4], p1[4];
#pragma unroll
        for (int p = 0; p < 4; p++) {
            p0[p] = pk2(P[2 * p], P[2 * p + 1]);
            p1[p] = pk2(P[8 + 2 * p], P[8 + 2 * p + 1]);
        }
        PB0 = mk8(p0[0], p0[1], p0[2], p0[3]);
        PB1 = mk8(p1[0], p1[1], p1[2], p1[3]);
    }
    f16x8 Srw0 = FRAG(32), Srw1 = FRAG(33);
    // E[c][q]: lane&31 = q, reg -> c = (reg&3) + 8*(reg>>2) + 4*half_
    f32x16 E = mfma16(PB0, Srw0, mfma16(PB1, Srw1, zero16()));

    // per-lane column-sign dot: SM bit c = par(c & Mcol_q), q = col (lane&31)
    u32 SM = (col == 0 || col == 9) ? 0x96696996u
             : (col == 5)           ? 0xFFFF0000u
             : (col == 6)           ? 0x00FFFF00u
             : (col == 7)           ? 0xF00F0FF0u
             : (col == 8)           ? 0x3CC3C33Cu
                                    : 0u;
    u32 SMh = SM >> (half_ * 4);  // absorb c's +4*half_ bit
    float acc0 = 0.f, acc1 = 0.f;
#pragma unroll
    for (int i = 0; i < 16; i++) {
        const int ci = (i & 3) + 8 * (i >> 2);  // c = ci + 4*half_
        u32 m = (SMh << (31 - ci)) & 0x80000000u;
        float v = __uint_as_float(__float_as_uint(E[i]) ^ m);
        if (i & 1) acc1 += v; else acc0 += v;
    }
    float acc = acc0 + acc1;
    float tot = acc + __shfl(acc, lane ^ 32, 64);  // combine the two row-halves
    if (lane < NQ) out[wave * NQ + lane] = tot;
}

extern "C" void kernel_launch(void* const* d_in, const int* in_sizes, int n_in,
                              void* d_out, int out_size, void* d_ws, size_t ws_size,
                              hipStream_t stream) {
    const float* x = (const float*)d_in[0];
    const float* encW = (const float*)d_in[1];
    const float* encb = (const float*)d_in[2];
    const float* th = (const float*)d_in[3];
    float* out = (float*)d_out;
    uint16_t* frag = (uint16_t*)d_ws;  // 42 frags * 64 lanes * 8 f16 = 43008 B
    int batch = in_sizes[0] / 3;

    tq_prep<<<8, 256, 0, stream>>>(th, frag);
    int total_threads = batch * 64;
    tq_main<<<(total_threads + 255) / 256, 256, 0, stream>>>(x, encW, encb, frag, out, batch);
}

// Round 6
// 96.868 us; speedup vs baseline: 1.0201x; 1.0201x over previous
//
#include <hip/hip_runtime.h>
#include <stdint.h>

#define NQ 10
#define NL 4

typedef unsigned int u32;
typedef _Float16 f16x8 __attribute__((ext_vector_type(8)));
typedef float f32x16 __attribute__((ext_vector_type(16)));
typedef u32 u32x4 __attribute__((ext_vector_type(4)));

// CNOT-ring permutation F = X ∘ (Gray⊗Gray), gather convention (R10/R11-validated):
// Gray folded into prep; runtime X: row ^= C0*16, col ^= R0*31, in registers.
//
// sigma slot-order (R12): every MFMA operand fragment uses slot->k map
// sigma(s): k = kh*16 + j2*8 + hf*4 + j1j0. A C-layout output value gi lands at
// A-frag slot (kh=gi>>3, j=gi&7) in the SAME lane -> layout conversion = pk2 only.
//
// X-step (R6, re-verified incl. remote-lane parity flip): with
//   A = mixhl(swz(w0), w0), B = mixhl(swz(w1), w1):
//   frag0 = c0 ? B : A,  frag1 = c0 ? A : B.
// Identical words to the R2/R5 form (hi16 comes from lane^31 whose c0 is
// negated), but swz issues straight off pk2 -> shorter serial chain.
//
// Epilogue (R1-validated): E = mfma(P as A, Srow as B) -> E[c][q], q = lane.
// Column signs via parity words SM(Mcol_q); one shfl(^32); lanes 0..9 store.
//
// R6: shared zero accumulator Z. MFMA's D and C are separate operands, so
// Tr = mfma(a,b,Z) initializes the accumulator without 16 v_movs. Removes
// 256 zero-init moves/wave (~8% of issue budget). Z = +16 live regs; current
// residency band (3 waves/SIMD) tolerates this.
//
// Bisect history: nVi frags exonerated (R5 PASS); R3/R4 failures convicted on
// __launch_bounds__(256,4) forced reg-cap (miscompile under pressure).
// HARD CONSTRAINTS: frag table <= 46 frags (ws >= 47104 B proven by R1);
// never force waves-per-EU via launch_bounds on this kernel.
// frag table (42): f = l*8 + mat*4 + part*2 + kh (0..31); 32,33 = Srow;
//                  34 + l*2 + kh = nVi (exact -Vi).
//
// F^-1 row sign masks (Srow frags): Mrow: q0=0x0F q1=0x18 q2=0x1C q3=0x1E q>=4=0x1F

// ---------- helpers ----------
__device__ __forceinline__ f32x16 mfma16(f16x8 a, f16x8 b, f32x16 c) {
    return __builtin_amdgcn_mfma_f32_32x32x16_f16(a, b, c, 0, 0, 0);
}
__device__ __forceinline__ f32x16 zero16() {
    f32x16 z;
#pragma unroll
    for (int i = 0; i < 16; i++) z[i] = 0.f;
    return z;
}
__device__ __forceinline__ f16x8 negf(f16x8 v) {
    u32x4 u = __builtin_bit_cast(u32x4, v);
#pragma unroll
    for (int i = 0; i < 4; i++) u[i] ^= 0x80008000u;
    return __builtin_bit_cast(f16x8, u);
}
__device__ __forceinline__ u32 pk2(float a, float b) {
    auto h = __builtin_amdgcn_cvt_pkrtz(a, b);
    return __builtin_bit_cast(u32, h);
}
// result = lo16(x) | hi16(s)<<16
__device__ __forceinline__ u32 mixhl(u32 s, u32 x) {
    return __builtin_amdgcn_perm(s, x, 0x07060100u);
}
__device__ __forceinline__ f16x8 mk8(u32 a, u32 b, u32 c, u32 d) {
    u32x4 v; v[0] = a; v[1] = b; v[2] = c; v[3] = d;
    return __builtin_bit_cast(f16x8, v);
}
template <int MASK>
__device__ __forceinline__ u32 swzu(u32 v) {
    return (u32)__builtin_amdgcn_ds_swizzle((int)v, (MASK << 10) | 0x1F);
}
__device__ __forceinline__ void cmulh(float ar, float ai, float br, float bi, float& cr, float& ci) {
    cr = ar * br - ai * bi;
    ci = ar * bi + ai * br;
}

// ---------- prep: fused gates -> W,V frags (+ nVi copies, Srow) in d_ws ----------
// Launch <<<8,256>>> (2048-thread index space). Every block computes its own g[].
__global__ void tq_prep(const float* __restrict__ theta, uint16_t* __restrict__ frag) {
    __shared__ float g[NL * NQ][8];
    int tt = threadIdx.x;
    if (tt < NL * NQ) {
        float hx = 0.5f * theta[tt * 3 + 0];
        float hy = 0.5f * theta[tt * 3 + 1];
        float hz = 0.5f * theta[tt * 3 + 2];
        float cx = cosf(hx), sx = sinf(hx);
        float cy = cosf(hy), sy = sinf(hy);
        float cz = cosf(hz), sz = sinf(hz);
        float m00r = cx * cy, m00i = -sx * sy;
        float m01r = -cx * sy, m01i = -sx * cy;
        float m10r = cx * sy, m10i = -sx * cy;
        float m11r = cx * cy, m11i = sx * sy;
        float g00r, g00i, g01r, g01i, g10r, g10i, g11r, g11i;
        cmulh(m00r, m00i, cz, -sz, g00r, g00i);
        cmulh(m10r, m10i, cz, -sz, g10r, g10i);
        cmulh(m01r, m01i, cz, sz, g01r, g01i);
        cmulh(m11r, m11i, cz, sz, g11r, g11i);
        g[tt][0] = g00r; g[tt][1] = g00i; g[tt][2] = g01r; g[tt][3] = g01i;
        g[tt][4] = g10r; g[tt][5] = g10i; g[tt][6] = g11r; g[tt][7] = g11i;
    }
    __syncthreads();
    int t = blockIdx.x * blockDim.x + tt;  // 0..2047
    int lane = t & 63, kh = (t >> 6) & 1, part = (t >> 7) & 1, mat = (t >> 8) & 1, l = t >> 9;
    int mn = lane & 31, hf = (lane >> 5) & 1;
    int mne = (l < NL - 1) ? ((mn ^ (mn >> 1)) & 31) : mn;  // Gray fold for layers 0..2
    // negated copy only for Vi (mat=1, part=1): f = 34 + l*2 + kh  (42 frags total)
    uint16_t* nout = (part == 1 && mat == 1)
                         ? (frag + (((34 + l * 2 + kh) * 64) + lane) * 8)
                         : (uint16_t*)0;
#pragma unroll
    for (int j = 0; j < 8; j++) {
        int k = kh * 16 + ((j >> 2)) * 8 + hf * 4 + (j & 3);  // sigma(slot)
        float pr = 1.f, pi = 0.f;
#pragma unroll
        for (int u = 0; u < 5; u++) {
            int q = mat ? (5 + u) : u;
            int bi_ = (k >> (4 - u)) & 1;
            int bo_ = (mne >> (4 - u)) & 1;
            const float* gg = g[l * NQ + q];
            float er = gg[(bi_ * 2 + bo_) * 2 + 0];
            float ei = gg[(bi_ * 2 + bo_) * 2 + 1];
            float nr, ni;
            cmulh(pr, pi, er, ei, nr, ni);
            pr = nr;
            pi = ni;
        }
        float v = part ? pi : pr;
        _Float16 h = (_Float16)v;
        unsigned short hb = __builtin_bit_cast(unsigned short, h);
        frag[t * 8 + j] = hb;
        if (nout) nout[j] = hb ^ 0x8000u;  // exact sign flip
    }
    // Srow sign frags (f=32,33): element(lane q, slot s) = (-1)^par(sigma(s) & Mrow(q))
    if (blockIdx.x == 0 && tt < 128) {
        int ln = tt & 63, kh2 = tt >> 6;
        int q = ln & 31, hf2 = (ln >> 5) & 1;
        u32 M = (q == 0) ? 0xFu : (q == 1) ? 0x18u : (q == 2) ? 0x1Cu : (q == 3) ? 0x1Eu : 0x1Fu;
        uint16_t* o = frag + ((32 + kh2) * 64 + ln) * 8;
#pragma unroll
        for (int j = 0; j < 8; j++) {
            int k = kh2 * 16 + ((j >> 2)) * 8 + hf2 * 4 + (j & 3);  // sigma(slot)
            float v = (__builtin_popcount((u32)k & M) & 1) ? -1.f : 1.f;
            _Float16 h = (_Float16)v;
            o[j] = __builtin_bit_cast(unsigned short, h);
        }
    }
}

// ---------- main: one wave per sample; zero LDS allocation ----------
__global__ __launch_bounds__(256) void tq_main(
    const float* __restrict__ x, const float* __restrict__ encW,
    const float* __restrict__ encb, const uint16_t* __restrict__ frag,
    float* __restrict__ out, int batch) {
    int tid = threadIdx.x;
    int wave = (blockIdx.x * blockDim.x + tid) >> 6;
    int lane = tid & 63;
    if (wave >= batch) return;
    const int col = lane & 31;
    const int half_ = lane >> 5;
    const bool c0 = (lane & 1) != 0;

    // ---- encoding: RY(enc) product state, built directly as sigma-slot A-frag ----
    float x0 = x[wave * 3 + 0], x1 = x[wave * 3 + 1], x2 = x[wave * 3 + 2];
    float hc = 1.f, hs = 0.f;
    if (lane < NQ) {
        float tta = 3.14159265358979323846f *
                    tanhf(x0 * encW[lane * 3 + 0] + x1 * encW[lane * 3 + 1] +
                          x2 * encW[lane * 3 + 2] + encb[lane]);
        float h = 0.5f * tta;
        hc = cosf(h);
        hs = sinf(h);
    }
    float fcv[NQ], fsv[NQ];
#pragma unroll
    for (int q = 0; q < NQ; q++) {
        fcv[q] = __shfl(hc, q, 64);
        fsv[q] = __shfl(hs, q, 64);
    }
    float colf = 1.f;
    colf *= ((col >> 4) & 1) ? -fsv[5] : fcv[5];
    colf *= ((col >> 3) & 1) ? -fsv[6] : fcv[6];
    colf *= ((col >> 2) & 1) ? -fsv[7] : fcv[7];
    colf *= ((col >> 1) & 1) ? -fsv[8] : fcv[8];
    colf *= (col & 1) ? -fsv[9] : fcv[9];
    // row r = sigma(slot): q0<-kh, q1<-j2, q2<-hf, q3<-j1, q4<-j0
    float f2h = half_ ? -fsv[2] : fcv[2];
    float gj[8];
#pragma unroll
    for (int j = 0; j < 8; j++) {
        gj[j] = ((j & 4) ? -fsv[1] : fcv[1]) * ((j & 2) ? -fsv[3] : fcv[3]) *
                ((j & 1) ? -fsv[4] : fcv[4]);
    }
    f16x8 Sr0, Sr1, Si0, Si1;
#pragma unroll
    for (int j = 0; j < 8; j++) {
        Sr0[j] = (_Float16)(fcv[0] * f2h * gj[j] * colf);
        Sr1[j] = (_Float16)(-fsv[0] * f2h * gj[j] * colf);
        Si0[j] = (_Float16)0.f;
        Si1[j] = (_Float16)0.f;
    }

    const f16x8* fr = (const f16x8*)frag;
#define FRAG(f) fr[((f)*64) + lane]

    const f32x16 Z = zero16();  // shared zero C-operand: D := A*B + Z, D != Z

    f32x16 Ur, Ui;
#pragma unroll
    for (int l = 0; l < NL; l++) {
        f16x8 Wr0 = FRAG(8 * l + 0), Wr1 = FRAG(8 * l + 1);
        f16x8 Wi0 = FRAG(8 * l + 2), Wi1 = FRAG(8 * l + 3);
        f16x8 Vr0 = FRAG(8 * l + 4), Vr1 = FRAG(8 * l + 5);
        f16x8 Vi0 = FRAG(8 * l + 6), Vi1 = FRAG(8 * l + 7);
        f16x8 nVi0 = FRAG(34 + l * 2 + 0), nVi1 = FRAG(34 + l * 2 + 1);

        // GEMM1': T' = S^T * W^T = T^T (S-frag as A; W-frag as B; both sigma-ordered)
        f32x16 Tr = mfma16(Sr0, Wr0, Z);
        Tr = mfma16(Sr1, Wr1, Tr);
        f32x16 Ti = mfma16(Sr0, Wi0, Z);
        Ti = mfma16(Sr1, Wi1, Ti);
        if (l > 0) {
            f16x8 nSi0 = negf(Si0), nSi1 = negf(Si1);  // off critical path
            Tr = mfma16(nSi0, Wi0, Tr);
            Tr = mfma16(nSi1, Wi1, Tr);
            Ti = mfma16(Si0, Wr0, Ti);
            Ti = mfma16(Si1, Wr1, Ti);
        }

        // C(T') -> sigma-slot A-frag(T): pure pack, same lane (no DS, no selects)
        f16x8 TAr0, TAr1, TAi0, TAi1;
        {
            u32 a0[4], a1[4], b0[4], b1[4];
#pragma unroll
            for (int p = 0; p < 4; p++) {
                a0[p] = pk2(Tr[2 * p], Tr[2 * p + 1]);
                a1[p] = pk2(Tr[8 + 2 * p], Tr[8 + 2 * p + 1]);
                b0[p] = pk2(Ti[2 * p], Ti[2 * p + 1]);
                b1[p] = pk2(Ti[8 + 2 * p], Ti[8 + 2 * p + 1]);
            }
            TAr0 = mk8(a0[0], a0[1], a0[2], a0[3]);
            TAr1 = mk8(a1[0], a1[1], a1[2], a1[3]);
            TAi0 = mk8(b0[0], b0[1], b0[2], b0[3]);
            TAi1 = mk8(b1[0], b1[1], b1[2], b1[3]);
        }

        // GEMM2: U = T * V (imag negation via static nVi frags, exact:
        // TAi*(-Vi) == (-TAi)*Vi; removes 8 xors from the pack->GEMM2 path)
        Ur = mfma16(TAr0, Vr0, Z);
        Ur = mfma16(TAr1, Vr1, Ur);
        Ur = mfma16(TAi0, nVi0, Ur);
        Ur = mfma16(TAi1, nVi1, Ur);
        Ui = mfma16(TAr0, Vi0, Z);
        Ui = mfma16(TAr1, Vi1, Ui);
        Ui = mfma16(TAi0, Vr0, Ui);
        Ui = mfma16(TAi1, Vr1, Ui);

        if (l < NL - 1) {
            // X-step + sigma A-frag assembly (R6 short form, re-verified):
            // A = mixhl(swz(w0), w0), B = mixhl(swz(w1), w1);
            // frag0 = c0 ? B : A, frag1 = c0 ? A : B.
            // (hi16 arrives from lane^31 whose c0 is negated -> the swizzled
            // word is the UNCONDITIONAL w0/w1; select happens after.)
            u32 wr0[4], wr1[4], wi0[4], wi1[4];
#pragma unroll
            for (int p = 0; p < 4; p++) {
                wr0[p] = pk2(Ur[2 * p], Ur[2 * p + 1]);
                wr1[p] = pk2(Ur[8 + 2 * p], Ur[8 + 2 * p + 1]);
                wi0[p] = pk2(Ui[2 * p], Ui[2 * p + 1]);
                wi1[p] = pk2(Ui[8 + 2 * p], Ui[8 + 2 * p + 1]);
            }
            u32 s0[4], s1[4], t0[4], t1[4];
#pragma unroll
            for (int p = 0; p < 4; p++) {
                u32 Ar = mixhl(swzu<0x1F>(wr0[p]), wr0[p]);
                u32 Br = mixhl(swzu<0x1F>(wr1[p]), wr1[p]);
                u32 Ai = mixhl(swzu<0x1F>(wi0[p]), wi0[p]);
                u32 Bi = mixhl(swzu<0x1F>(wi1[p]), wi1[p]);
                s0[p] = c0 ? Br : Ar;
                s1[p] = c0 ? Ar : Br;
                t0[p] = c0 ? Bi : Ai;
                t1[p] = c0 ? Ai : Bi;
            }
            Sr0 = mk8(s0[0], s0[1], s0[2], s0[3]);
            Sr1 = mk8(s1[0], s1[1], s1[2], s1[3]);
            Si0 = mk8(t0[0], t0[1], t0[2], t0[3]);
            Si1 = mk8(t1[0], t1[1], t1[2], t1[3]);
        }
    }

    // ---- epilogue: E = P^T * Srow^T via MFMA(P as A, Srow as B) -> q = lane ----
    f32x16 P;
#pragma unroll
    for (int gi = 0; gi < 16; gi++) P[gi] = Ur[gi] * Ur[gi] + Ui[gi] * Ui[gi];
    f16x8 PB0, PB1;
    {
        u32 p0[4], p1[4];
#pragma unroll
        for (int p = 0; p < 4; p++) {
            p0[p] = pk2(P[2 * p], P[2 * p + 1]);
            p1[p] = pk2(P[8 + 2 * p], P[8 + 2 * p + 1]);
        }
        PB0 = mk8(p0[0], p0[1], p0[2], p0[3]);
        PB1 = mk8(p1[0], p1[1], p1[2], p1[3]);
    }
    f16x8 Srw0 = FRAG(32), Srw1 = FRAG(33);
    // E[c][q]: lane&31 = q, reg -> c = (reg&3) + 8*(reg>>2) + 4*half_
    f32x16 E = mfma16(PB0, Srw0, mfma16(PB1, Srw1, Z));

    // per-lane column-sign dot: SM bit c = par(c & Mcol_q), q = col (lane&31)
    u32 SM = (col == 0 || col == 9) ? 0x96696996u
             : (col == 5)           ? 0xFFFF0000u
             : (col == 6)           ? 0x00FFFF00u
             : (col == 7)           ? 0xF00F0FF0u
             : (col == 8)           ? 0x3CC3C33Cu
                                    : 0u;
    u32 SMh = SM >> (half_ * 4);  // absorb c's +4*half_ bit
    float acc0 = 0.f, acc1 = 0.f;
#pragma unroll
    for (int i = 0; i < 16; i++) {
        const int ci = (i & 3) + 8 * (i >> 2);  // c = ci + 4*half_
        u32 m = (SMh << (31 - ci)) & 0x80000000u;
        float v = __uint_as_float(__float_as_uint(E[i]) ^ m);
        if (i & 1) acc1 += v; else acc0 += v;
    }
    float acc = acc0 + acc1;
    float tot = acc + __shfl(acc, lane ^ 32, 64);  // combine the two row-halves
    if (lane < NQ) out[wave * NQ + lane] = tot;
}

extern "C" void kernel_launch(void* const* d_in, const int* in_sizes, int n_in,
                              void* d_out, int out_size, void* d_ws, size_t ws_size,
                              hipStream_t stream) {
    const float* x = (const float*)d_in[0];
    const float* encW = (const float*)d_in[1];
    const float* encb = (const float*)d_in[2];
    const float* th = (const float*)d_in[3];
    float* out = (float*)d_out;
    uint16_t* frag = (uint16_t*)d_ws;  // 42 frags * 64 lanes * 8 f16 = 43008 B
    int batch = in_sizes[0] / 3;

    tq_prep<<<8, 256, 0, stream>>>(th, frag);
    int total_threads = batch * 64;
    tq_main<<<(total_threads + 255) / 256, 256, 0, stream>>>(x, encW, encb, frag, out, batch);
}

// Round 7
// 96.717 us; speedup vs baseline: 1.0217x; 1.0016x over previous
//
#include <hip/hip_runtime.h>
#include <stdint.h>

#define NQ 10
#define NL 4

typedef unsigned int u32;
typedef _Float16 f16x8 __attribute__((ext_vector_type(8)));
typedef float f32x16 __attribute__((ext_vector_type(16)));
typedef u32 u32x4 __attribute__((ext_vector_type(4)));

// CNOT-ring permutation F = X ∘ (Gray⊗Gray), gather convention (R10/R11-validated):
// Gray folded into prep; runtime X: row ^= C0*16, col ^= R0*31, in registers.
//
// sigma slot-order (R12): every MFMA operand fragment uses slot->k map
// sigma(s): k = kh*16 + j2*8 + hf*4 + j1j0. A C-layout output value gi lands at
// A-frag slot (kh=gi>>3, j=gi&7) in the SAME lane -> layout conversion = pk2 only.
//
// X-step (R6-validated short form): A = mixhl(swz(w0), w0), B = mixhl(swz(w1), w1);
// frag0 = c0 ? B : A, frag1 = c0 ? A : B. (hi16 arrives from lane^31 whose c0
// is negated -> swizzled word is the UNCONDITIONAL w0/w1; select after.)
//
// Epilogue (R1-validated): E = mfma(P as A, Srow as B) -> E[c][q], q = lane.
// Column signs via parity words SM(Mcol_q); one shfl(^32); lanes 0..9 store.
//
// R7: prep parallelized 8x (j-loop split across threads; 16384 threads, 64
// blocks). Frag values bit-identical (same serial cmul order). Main kernel is
// byte-for-byte R6 (40.8 us, MfmaUtil 33%, VALUBusy 58%, combined ~91%).
// Bench model: dur_us ~= 2*(prep+main) + launch; prep was 8 blocks @ 1 wave/SIMD
// with a ~300-op serial chain -> the only cheap lever left.
//
// Bisect history: nVi frags exonerated (R5); R3/R4 failures convicted on
// __launch_bounds__(256,4) forced reg-cap (miscompile under pressure).
// HARD CONSTRAINTS: frag table <= 46 frags (ws >= 47104 B proven by R1);
// never force waves-per-EU via launch_bounds on this kernel.
// frag table (42): f = l*8 + mat*4 + part*2 + kh (0..31); 32,33 = Srow;
//                  34 + l*2 + kh = nVi (exact -Vi).
//
// F^-1 row sign masks (Srow frags): Mrow: q0=0x0F q1=0x18 q2=0x1C q3=0x1E q>=4=0x1F

// ---------- helpers ----------
__device__ __forceinline__ f32x16 mfma16(f16x8 a, f16x8 b, f32x16 c) {
    return __builtin_amdgcn_mfma_f32_32x32x16_f16(a, b, c, 0, 0, 0);
}
__device__ __forceinline__ f32x16 zero16() {
    f32x16 z;
#pragma unroll
    for (int i = 0; i < 16; i++) z[i] = 0.f;
    return z;
}
__device__ __forceinline__ f16x8 negf(f16x8 v) {
    u32x4 u = __builtin_bit_cast(u32x4, v);
#pragma unroll
    for (int i = 0; i < 4; i++) u[i] ^= 0x80008000u;
    return __builtin_bit_cast(f16x8, u);
}
__device__ __forceinline__ u32 pk2(float a, float b) {
    auto h = __builtin_amdgcn_cvt_pkrtz(a, b);
    return __builtin_bit_cast(u32, h);
}
// result = lo16(x) | hi16(s)<<16
__device__ __forceinline__ u32 mixhl(u32 s, u32 x) {
    return __builtin_amdgcn_perm(s, x, 0x07060100u);
}
__device__ __forceinline__ f16x8 mk8(u32 a, u32 b, u32 c, u32 d) {
    u32x4 v; v[0] = a; v[1] = b; v[2] = c; v[3] = d;
    return __builtin_bit_cast(f16x8, v);
}
template <int MASK>
__device__ __forceinline__ u32 swzu(u32 v) {
    return (u32)__builtin_amdgcn_ds_swizzle((int)v, (MASK << 10) | 0x1F);
}
__device__ __forceinline__ void cmulh(float ar, float ai, float br, float bi, float& cr, float& ci) {
    cr = ar * br - ai * bi;
    ci = ar * bi + ai * br;
}

// ---------- prep: fused gates -> W,V frags (+ nVi copies, Srow) in d_ws ----------
// R7: one thread per (frag element): tid = t*8 + j, 16384 threads, <<<64,256>>>.
// Serial chain per thread = 5 cmuls (was 8x that); store frag[tid] coalesced.
__global__ void tq_prep(const float* __restrict__ theta, uint16_t* __restrict__ frag) {
    __shared__ float g[NL * NQ][8];
    int tt = threadIdx.x;
    if (tt < NL * NQ) {
        float hx = 0.5f * theta[tt * 3 + 0];
        float hy = 0.5f * theta[tt * 3 + 1];
        float hz = 0.5f * theta[tt * 3 + 2];
        float cx = cosf(hx), sx = sinf(hx);
        float cy = cosf(hy), sy = sinf(hy);
        float cz = cosf(hz), sz = sinf(hz);
        float m00r = cx * cy, m00i = -sx * sy;
        float m01r = -cx * sy, m01i = -sx * cy;
        float m10r = cx * sy, m10i = -sx * cy;
        float m11r = cx * cy, m11i = sx * sy;
        float g00r, g00i, g01r, g01i, g10r, g10i, g11r, g11i;
        cmulh(m00r, m00i, cz, -sz, g00r, g00i);
        cmulh(m10r, m10i, cz, -sz, g10r, g10i);
        cmulh(m01r, m01i, cz, sz, g01r, g01i);
        cmulh(m11r, m11i, cz, sz, g11r, g11i);
        g[tt][0] = g00r; g[tt][1] = g00i; g[tt][2] = g01r; g[tt][3] = g01i;
        g[tt][4] = g10r; g[tt][5] = g10i; g[tt][6] = g11r; g[tt][7] = g11i;
    }
    __syncthreads();
    int tid = blockIdx.x * blockDim.x + tt;  // 0..16383 = t*8 + j
    int t = tid >> 3, j = tid & 7;
    int lane = t & 63, kh = (t >> 6) & 1, part = (t >> 7) & 1, mat = (t >> 8) & 1, l = t >> 9;
    int mn = lane & 31, hf = (lane >> 5) & 1;
    int mne = (l < NL - 1) ? ((mn ^ (mn >> 1)) & 31) : mn;  // Gray fold for layers 0..2

    int k = kh * 16 + ((j >> 2)) * 8 + hf * 4 + (j & 3);  // sigma(slot)
    float pr = 1.f, pi = 0.f;
#pragma unroll
    for (int u = 0; u < 5; u++) {
        int q = mat ? (5 + u) : u;
        int bi_ = (k >> (4 - u)) & 1;
        int bo_ = (mne >> (4 - u)) & 1;
        const float* gg = g[l * NQ + q];
        float er = gg[(bi_ * 2 + bo_) * 2 + 0];
        float ei = gg[(bi_ * 2 + bo_) * 2 + 1];
        float nr, ni;
        cmulh(pr, pi, er, ei, nr, ni);
        pr = nr;
        pi = ni;
    }
    float v = part ? pi : pr;
    _Float16 h = (_Float16)v;
    unsigned short hb = __builtin_bit_cast(unsigned short, h);
    frag[tid] = hb;
    // negated copy only for Vi (mat=1, part=1): f = 34 + l*2 + kh  (42 frags total)
    if (part == 1 && mat == 1) {
        frag[(((34 + l * 2 + kh) * 64) + lane) * 8 + j] = hb ^ 0x8000u;  // exact -Vi
    }
    // Srow sign frags (f=32,33): element(lane q, slot s) = (-1)^par(sigma(s) & Mrow(q))
    if (blockIdx.x == 0 && tt < 128) {
        int ln = tt & 63, kh2 = tt >> 6;
        int q = ln & 31, hf2 = (ln >> 5) & 1;
        u32 M = (q == 0) ? 0xFu : (q == 1) ? 0x18u : (q == 2) ? 0x1Cu : (q == 3) ? 0x1Eu : 0x1Fu;
        uint16_t* o = frag + ((32 + kh2) * 64 + ln) * 8;
#pragma unroll
        for (int jj = 0; jj < 8; jj++) {
            int kk = kh2 * 16 + ((jj >> 2)) * 8 + hf2 * 4 + (jj & 3);  // sigma(slot)
            float sv = (__builtin_popcount((u32)kk & M) & 1) ? -1.f : 1.f;
            _Float16 hh = (_Float16)sv;
            o[jj] = __builtin_bit_cast(unsigned short, hh);
        }
    }
}

// ---------- main: one wave per sample; zero LDS allocation (byte-for-byte R6) ----------
__global__ __launch_bounds__(256) void tq_main(
    const float* __restrict__ x, const float* __restrict__ encW,
    const float* __restrict__ encb, const uint16_t* __restrict__ frag,
    float* __restrict__ out, int batch) {
    int tid = threadIdx.x;
    int wave = (blockIdx.x * blockDim.x + tid) >> 6;
    int lane = tid & 63;
    if (wave >= batch) return;
    const int col = lane & 31;
    const int half_ = lane >> 5;
    const bool c0 = (lane & 1) != 0;

    // ---- encoding: RY(enc) product state, built directly as sigma-slot A-frag ----
    float x0 = x[wave * 3 + 0], x1 = x[wave * 3 + 1], x2 = x[wave * 3 + 2];
    float hc = 1.f, hs = 0.f;
    if (lane < NQ) {
        float tta = 3.14159265358979323846f *
                    tanhf(x0 * encW[lane * 3 + 0] + x1 * encW[lane * 3 + 1] +
                          x2 * encW[lane * 3 + 2] + encb[lane]);
        float h = 0.5f * tta;
        hc = cosf(h);
        hs = sinf(h);
    }
    float fcv[NQ], fsv[NQ];
#pragma unroll
    for (int q = 0; q < NQ; q++) {
        fcv[q] = __shfl(hc, q, 64);
        fsv[q] = __shfl(hs, q, 64);
    }
    float colf = 1.f;
    colf *= ((col >> 4) & 1) ? -fsv[5] : fcv[5];
    colf *= ((col >> 3) & 1) ? -fsv[6] : fcv[6];
    colf *= ((col >> 2) & 1) ? -fsv[7] : fcv[7];
    colf *= ((col >> 1) & 1) ? -fsv[8] : fcv[8];
    colf *= (col & 1) ? -fsv[9] : fcv[9];
    // row r = sigma(slot): q0<-kh, q1<-j2, q2<-hf, q3<-j1, q4<-j0
    float f2h = half_ ? -fsv[2] : fcv[2];
    float gj[8];
#pragma unroll
    for (int j = 0; j < 8; j++) {
        gj[j] = ((j & 4) ? -fsv[1] : fcv[1]) * ((j & 2) ? -fsv[3] : fcv[3]) *
                ((j & 1) ? -fsv[4] : fcv[4]);
    }
    f16x8 Sr0, Sr1, Si0, Si1;
#pragma unroll
    for (int j = 0; j < 8; j++) {
        Sr0[j] = (_Float16)(fcv[0] * f2h * gj[j] * colf);
        Sr1[j] = (_Float16)(-fsv[0] * f2h * gj[j] * colf);
        Si0[j] = (_Float16)0.f;
        Si1[j] = (_Float16)0.f;
    }

    const f16x8* fr = (const f16x8*)frag;
#define FRAG(f) fr[((f)*64) + lane]

    const f32x16 Z = zero16();  // shared zero C-operand: D := A*B + Z, D != Z

    f32x16 Ur, Ui;
#pragma unroll
    for (int l = 0; l < NL; l++) {
        f16x8 Wr0 = FRAG(8 * l + 0), Wr1 = FRAG(8 * l + 1);
        f16x8 Wi0 = FRAG(8 * l + 2), Wi1 = FRAG(8 * l + 3);
        f16x8 Vr0 = FRAG(8 * l + 4), Vr1 = FRAG(8 * l + 5);
        f16x8 Vi0 = FRAG(8 * l + 6), Vi1 = FRAG(8 * l + 7);
        f16x8 nVi0 = FRAG(34 + l * 2 + 0), nVi1 = FRAG(34 + l * 2 + 1);

        // GEMM1': T' = S^T * W^T = T^T (S-frag as A; W-frag as B; both sigma-ordered)
        f32x16 Tr = mfma16(Sr0, Wr0, Z);
        Tr = mfma16(Sr1, Wr1, Tr);
        f32x16 Ti = mfma16(Sr0, Wi0, Z);
        Ti = mfma16(Sr1, Wi1, Ti);
        if (l > 0) {
            f16x8 nSi0 = negf(Si0), nSi1 = negf(Si1);  // off critical path
            Tr = mfma16(nSi0, Wi0, Tr);
            Tr = mfma16(nSi1, Wi1, Tr);
            Ti = mfma16(Si0, Wr0, Ti);
            Ti = mfma16(Si1, Wr1, Ti);
        }

        // C(T') -> sigma-slot A-frag(T): pure pack, same lane (no DS, no selects)
        f16x8 TAr0, TAr1, TAi0, TAi1;
        {
            u32 a0[4], a1[4], b0[4], b1[4];
#pragma unroll
            for (int p = 0; p < 4; p++) {
                a0[p] = pk2(Tr[2 * p], Tr[2 * p + 1]);
                a1[p] = pk2(Tr[8 + 2 * p], Tr[8 + 2 * p + 1]);
                b0[p] = pk2(Ti[2 * p], Ti[2 * p + 1]);
                b1[p] = pk2(Ti[8 + 2 * p], Ti[8 + 2 * p + 1]);
            }
            TAr0 = mk8(a0[0], a0[1], a0[2], a0[3]);
            TAr1 = mk8(a1[0], a1[1], a1[2], a1[3]);
            TAi0 = mk8(b0[0], b0[1], b0[2], b0[3]);
            TAi1 = mk8(b1[0], b1[1], b1[2], b1[3]);
        }

        // GEMM2: U = T * V (imag negation via static nVi frags, exact:
        // TAi*(-Vi) == (-TAi)*Vi; removes 8 xors from the pack->GEMM2 path)
        Ur = mfma16(TAr0, Vr0, Z);
        Ur = mfma16(TAr1, Vr1, Ur);
        Ur = mfma16(TAi0, nVi0, Ur);
        Ur = mfma16(TAi1, nVi1, Ur);
        Ui = mfma16(TAr0, Vi0, Z);
        Ui = mfma16(TAr1, Vi1, Ui);
        Ui = mfma16(TAi0, Vr0, Ui);
        Ui = mfma16(TAi1, Vr1, Ui);

        if (l < NL - 1) {
            // X-step + sigma A-frag assembly (R6 short form, validated):
            // A = mixhl(swz(w0), w0), B = mixhl(swz(w1), w1);
            // frag0 = c0 ? B : A, frag1 = c0 ? A : B.
            u32 wr0[4], wr1[4], wi0[4], wi1[4];
#pragma unroll
            for (int p = 0; p < 4; p++) {
                wr0[p] = pk2(Ur[2 * p], Ur[2 * p + 1]);
                wr1[p] = pk2(Ur[8 + 2 * p], Ur[8 + 2 * p + 1]);
                wi0[p] = pk2(Ui[2 * p], Ui[2 * p + 1]);
                wi1[p] = pk2(Ui[8 + 2 * p], Ui[8 + 2 * p + 1]);
            }
            u32 s0[4], s1[4], t0[4], t1[4];
#pragma unroll
            for (int p = 0; p < 4; p++) {
                u32 Ar = mixhl(swzu<0x1F>(wr0[p]), wr0[p]);
                u32 Br = mixhl(swzu<0x1F>(wr1[p]), wr1[p]);
                u32 Ai = mixhl(swzu<0x1F>(wi0[p]), wi0[p]);
                u32 Bi = mixhl(swzu<0x1F>(wi1[p]), wi1[p]);
                s0[p] = c0 ? Br : Ar;
                s1[p] = c0 ? Ar : Br;
                t0[p] = c0 ? Bi : Ai;
                t1[p] = c0 ? Ai : Bi;
            }
            Sr0 = mk8(s0[0], s0[1], s0[2], s0[3]);
            Sr1 = mk8(s1[0], s1[1], s1[2], s1[3]);
            Si0 = mk8(t0[0], t0[1], t0[2], t0[3]);
            Si1 = mk8(t1[0], t1[1], t1[2], t1[3]);
        }
    }

    // ---- epilogue: E = P^T * Srow^T via MFMA(P as A, Srow as B) -> q = lane ----
    f32x16 P;
#pragma unroll
    for (int gi = 0; gi < 16; gi++) P[gi] = Ur[gi] * Ur[gi] + Ui[gi] * Ui[gi];
    f16x8 PB0, PB1;
    {
        u32 p0[4], p1[4];
#pragma unroll
        for (int p = 0; p < 4; p++) {
            p0[p] = pk2(P[2 * p], P[2 * p + 1]);
            p1[p] = pk2(P[8 + 2 * p], P[8 + 2 * p + 1]);
        }
        PB0 = mk8(p0[0], p0[1], p0[2], p0[3]);
        PB1 = mk8(p1[0], p1[1], p1[2], p1[3]);
    }
    f16x8 Srw0 = FRAG(32), Srw1 = FRAG(33);
    // E[c][q]: lane&31 = q, reg -> c = (reg&3) + 8*(reg>>2) + 4*half_
    f32x16 E = mfma16(PB0, Srw0, mfma16(PB1, Srw1, Z));

    // per-lane column-sign dot: SM bit c = par(c & Mcol_q), q = col (lane&31)
    u32 SM = (col == 0 || col == 9) ? 0x96696996u
             : (col == 5)           ? 0xFFFF0000u
             : (col == 6)           ? 0x00FFFF00u
             : (col == 7)           ? 0xF00F0FF0u
             : (col == 8)           ? 0x3CC3C33Cu
                                    : 0u;
    u32 SMh = SM >> (half_ * 4);  // absorb c's +4*half_ bit
    float acc0 = 0.f, acc1 = 0.f;
#pragma unroll
    for (int i = 0; i < 16; i++) {
        const int ci = (i & 3) + 8 * (i >> 2);  // c = ci + 4*half_
        u32 m = (SMh << (31 - ci)) & 0x80000000u;
        float v = __uint_as_float(__float_as_uint(E[i]) ^ m);
        if (i & 1) acc1 += v; else acc0 += v;
    }
    float acc = acc0 + acc1;
    float tot = acc + __shfl(acc, lane ^ 32, 64);  // combine the two row-halves
    if (lane < NQ) out[wave * NQ + lane] = tot;
}

extern "C" void kernel_launch(void* const* d_in, const int* in_sizes, int n_in,
                              void* d_out, int out_size, void* d_ws, size_t ws_size,
                              hipStream_t stream) {
    const float* x = (const float*)d_in[0];
    const float* encW = (const float*)d_in[1];
    const float* encb = (const float*)d_in[2];
    const float* th = (const float*)d_in[3];
    float* out = (float*)d_out;
    uint16_t* frag = (uint16_t*)d_ws;  // 42 frags * 64 lanes * 8 f16 = 43008 B
    int batch = in_sizes[0] / 3;

    tq_prep<<<64, 256, 0, stream>>>(th, frag);
    int total_threads = batch * 64;
    tq_main<<<(total_threads + 255) / 256, 256, 0, stream>>>(x, encW, encb, frag, out, batch);
}